// Round 8
// baseline (888.707 us; speedup 1.0000x reference)
//
#include <hip/hip_runtime.h>
#include <hip/hip_bf16.h>
#include <math.h>

#define NNODES 100000
#define NEDGES 1600000
#define FIN 256
#define HDIM 128
#define NGRAPH 128
#define NCLS 10
#define NEG 0.2f

#define NBUCK 98            // buckets of 1024 dst nodes
#define EPB 4096            // edges per bin_place block
#define EBLK ((NEDGES + EPB - 1) / EPB)   // 391

typedef short bf8 __attribute__((ext_vector_type(8)));
typedef float f4 __attribute__((ext_vector_type(4)));
typedef float f2v __attribute__((ext_vector_type(2)));

__device__ __forceinline__ float lrelu(float x) { return x > 0.f ? x : NEG * x; }

__device__ __forceinline__ unsigned short f2bf(float f) {
  union { float f; unsigned int u; } v; v.f = f;
  unsigned int r = v.u + 0x7fffu + ((v.u >> 16) & 1u);   // round-nearest-even
  return (unsigned short)(r >> 16);
}
__device__ __forceinline__ float bf2f(unsigned short u) {
  union { unsigned int u; float f; } v; v.u = ((unsigned int)u) << 16; return v.f;
}
__device__ __forceinline__ float fast_rcp(float x) {
  float r;
  asm("v_rcp_f32 %0, %1" : "=v"(r) : "v"(x));
  return r;
}
__device__ __forceinline__ unsigned cvt_pk_bf16(float lo, float hi) {
  unsigned r;
  asm("v_cvt_pk_bf16_f32 %0, %1, %2" : "=v"(r) : "v"(lo), "v"(hi));
  return r;
}
// fp8 e4m3 (OCP, gfx950 native) pack/unpack: value payload for the gather.
__device__ __forceinline__ unsigned short pk_fp8(float a, float b) {
  return (unsigned short)__builtin_amdgcn_cvt_pk_fp8_f32(a, b, 0, false);
}
__device__ __forceinline__ f2v pk_unpack_fp8(unsigned p) {
#if __has_builtin(__builtin_amdgcn_cvt_pk_f32_fp8)
  return __builtin_amdgcn_cvt_pk_f32_fp8((int)p, false);
#else
  f2v r;
  r.x = __builtin_amdgcn_cvt_f32_fp8(p, 0);
  r.y = __builtin_amdgcn_cvt_f32_fp8(p, 1);
  return r;
#endif
}
// direct global->LDS DMA, 16B/lane: dest = wave-uniform base + lane*16.
__device__ __forceinline__ void gload16(const void* gp, void* lp) {
  __builtin_amdgcn_global_load_lds(
      (const __attribute__((address_space(1))) void*)gp,
      (__attribute__((address_space(3))) void*)lp, 16, 0, 0);
}
// counted vmem wait (T4): keep N loads in flight, never drain mid-chunk.
// "memory" clobber + sched_barrier(0) pins subsequent ds_reads (rule #18).
template<int N>
__device__ __forceinline__ void vwait() {
  asm volatile("s_waitcnt vmcnt(%0)" :: "i"(N) : "memory");
  __builtin_amdgcn_sched_barrier(0);
}

// ---------------- one-shot weight convert+transpose: w[K][128] -> wt[128][K] -
__global__ __launch_bounds__(256) void convert_transpose(const float* __restrict__ w,
                                                         unsigned short* __restrict__ wt,
                                                         int K) {
  int i = blockIdx.x * 256 + threadIdx.x;
  if (i >= K * 128) return;
  int k = i >> 7, n = i & 127;
  wt[n * K + k] = f2bf(w[(size_t)k * 128 + n]);
}

// ---------------- MFMA GEMM: per-wave pipelined, counted vmcnt ---------------
// R3-R7 post-mortem: SIX structures all 62-81us, all pipes ~95% idle; the
// invariant was block-wide lockstep with an implicit vmcnt(0) drain per
// 32-K step -> in-flight depth 1. This version: A staging is WAVE-PRIVATE
// (each wave owns a 4-slot LDS ring), so the main loop has NO barriers; each
// wave issues global_load_lds 4 steps ahead and waits s_waitcnt vmcnt(N)
// counted so 3 steps stay in flight (guide T3/T4; never 0 mid-chunk).
// B (32KB per 128-K chunk, L2-resident) staged cooperatively, one barrier
// per chunk. In-flight/wave ~6-8KB -> ~32KB/CU (Little's law for ~700cy).
// Pooling (reprs += relu(h)) fused into the Cb epilogue via atomicAdd.
template<int K, int ABF16>
__global__ __launch_bounds__(256) void gemm_pipe(const void* __restrict__ Av,
                                                 const unsigned short* __restrict__ Bt,
                                                 const float* __restrict__ bias,
                                                 unsigned short* __restrict__ Cb,
                                                 unsigned short* __restrict__ Cp,
                                                 const float* __restrict__ a_src,
                                                 const float* __restrict__ a_dst,
                                                 float* __restrict__ o_as,
                                                 float* __restrict__ o_ad,
                                                 const int* __restrict__ batch,
                                                 float* __restrict__ reprs,
                                                 int M, int dorelu) {
  constexpr int NCH = K / 128;
  constexpr int L = ABF16 ? 1 : 2;            // gloads per A step per wave
  constexpr int ASLOT = ABF16 ? 1024 : 2048;  // bytes per ring slot
  constexpr int BSZ = 32768;                  // one 128-K chunk of B
  __shared__ alignas(16) char lds[BSZ + 16 * ASLOT];   // B + 4 waves x 4 slots
  int tid = threadIdx.x;
  int wv = tid >> 6, lane = tid & 63;
  int quad = lane >> 4, m16 = lane & 15;
  int row0 = blockIdx.x * 64;
  int rA = row0 + wv * 16 + m16; if (rA > M - 1) rA = M - 1;

  const unsigned short* Ab = (const unsigned short*)Av;
  const float* Af = (const float*)Av;

  auto stageBs = [&](int ch) {          // cooperative, blob j=(ktl*512+tn*64+l)
#pragma unroll
    for (int i2 = 0; i2 < 8; ++i2) {
      int j = i2 * 256 + tid;
      int l = j & 63, tn = (j >> 6) & 7, ktl = j >> 9;
      int n = tn * 16 + (l & 15);
      int k = ch * 128 + ktl * 32 + (l >> 4) * 8;
      *(bf8*)(lds + j * 16) = *(const bf8*)&Bt[(size_t)n * K + k];
    }
  };
  auto stageA = [&](int kt, int s) {    // wave-private ring slot s
    char* rb = lds + BSZ + (wv * 4 + s) * ASLOT;
    int kb = kt * 32;
    if (ABF16) {
      gload16(&Ab[(size_t)rA * K + kb + quad * 8], rb);
    } else {
      gload16(&Af[(size_t)rA * K + kb + quad * 8],     rb);
      gload16(&Af[(size_t)rA * K + kb + quad * 8 + 4], rb + 1024);
    }
  };

  f4 acc[8];
#pragma unroll
  for (int b = 0; b < 8; ++b) acc[b] = (f4){0.f, 0.f, 0.f, 0.f};

#define CONS(S, NW)                                                            \
  {                                                                            \
    vwait<NW>();                                                               \
    const char* rb = lds + BSZ + (wv * 4 + (S)) * ASLOT;                       \
    bf8 af;                                                                    \
    if (ABF16) {                                                               \
      af = *(const bf8*)(rb + lane * 16);                                      \
    } else {                                                                   \
      float4 x0 = *(const float4*)(rb + lane * 16);                            \
      float4 x1 = *(const float4*)(rb + 1024 + lane * 16);                     \
      union { bf8 v; unsigned u[4]; } rr;                                      \
      rr.u[0] = cvt_pk_bf16(x0.x, x0.y); rr.u[1] = cvt_pk_bf16(x0.z, x0.w);    \
      rr.u[2] = cvt_pk_bf16(x1.x, x1.y); rr.u[3] = cvt_pk_bf16(x1.z, x1.w);    \
      af = rr.v;                                                               \
    }                                                                          \
    _Pragma("unroll")                                                          \
    for (int tn = 0; tn < 8; ++tn) {                                           \
      bf8 bm = *(const bf8*)(lds + ((S) * 512 + tn * 64 + lane) * 16);         \
      acc[tn] = __builtin_amdgcn_mfma_f32_16x16x32_bf16(af, bm, acc[tn], 0, 0, 0); \
    }                                                                          \
  }

  stageBs(0);
  __syncthreads();
#pragma unroll
  for (int ch = 0; ch < NCH; ++ch) {
    if (ch) { __syncthreads(); stageBs(ch); __syncthreads(); }
    // prologue: issue all 4 A steps of this chunk (vmcnt clean at chunk start)
#pragma unroll
    for (int s = 0; s < 4; ++s) stageA(ch * 4 + s, s);
    // consume with counted waits: keep 3/2/1/0 steps in flight
    CONS(0, 3 * L);
    CONS(1, 2 * L);
    CONS(2, 1 * L);
    CONS(3, 0);
  }
#undef CONS

  if (Cp) {
    if (a_src) {
      float aS[8], aD[8];
#pragma unroll
      for (int tn = 0; tn < 4; ++tn) {
        aS[tn]     = a_src[tn * 16 + m16];
        aS[tn + 4] = a_src[64 + tn * 16 + m16];
        aD[tn]     = a_dst[tn * 16 + m16];
        aD[tn + 4] = a_dst[64 + tn * 16 + m16];
      }
#pragma unroll
      for (int r = 0; r < 4; ++r) {
        int row = row0 + wv * 16 + quad * 4 + r;
        float ps0 = 0.f, ps1 = 0.f, pd0 = 0.f, pd1 = 0.f;
#pragma unroll
        for (int tn = 0; tn < 4; ++tn) {
          float v0 = acc[tn][r], v1 = acc[tn + 4][r];
          ps0 = fmaf(v0, aS[tn], ps0);
          ps1 = fmaf(v1, aS[tn + 4], ps1);
          pd0 = fmaf(v0, aD[tn], pd0);
          pd1 = fmaf(v1, aD[tn + 4], pd1);
        }
#pragma unroll
        for (int o = 8; o; o >>= 1) {
          ps0 += __shfl_xor(ps0, o); ps1 += __shfl_xor(ps1, o);
          pd0 += __shfl_xor(pd0, o); pd1 += __shfl_xor(pd1, o);
        }
        if (m16 == 0 && row < M) {
          o_as[2 * row] = ps0; o_as[2 * row + 1] = ps1;
          o_ad[2 * row] = pd0; o_ad[2 * row + 1] = pd1;
        }
      }
    }
#pragma unroll
    for (int tn = 0; tn < 4; ++tn)
#pragma unroll
      for (int r = 0; r < 4; ++r) {
        int row = row0 + wv * 16 + quad * 4 + r;
        if (row < M) {
          Cp[(size_t)row * 64 + tn * 16 + m16] = pk_fp8(acc[tn][r], acc[tn + 4][r]);
        }
      }
  } else {
    int bR[4];
#pragma unroll
    for (int r = 0; r < 4; ++r) {
      int row = row0 + wv * 16 + quad * 4 + r;
      bR[r] = (row < M) ? batch[row] : 0;
    }
#pragma unroll
    for (int tn = 0; tn < 8; ++tn) {
      float bv = bias ? bias[tn * 16 + m16] : 0.f;
#pragma unroll
      for (int r = 0; r < 4; ++r) {
        int row = row0 + wv * 16 + quad * 4 + r;
        if (row < M) {
          float v = acc[tn][r] + bv;
          if (dorelu) v = fmaxf(v, 0.f);
          Cb[(size_t)row * 128 + tn * 16 + m16] = f2bf(v);
          atomicAdd(&reprs[bR[r] * 128 + tn * 16 + m16], v);   // fused pooling
        }
      }
    }
  }
}

// ======== CSR build, bucketed two-phase (no random global atomics) ==========
__global__ __launch_bounds__(256) void bin_count(const int* __restrict__ edst,
                                                 int* __restrict__ blockHist) {
  __shared__ int hist[NBUCK];
  int t = threadIdx.x, blk = blockIdx.x;
  if (t < NBUCK) hist[t] = 0;
  __syncthreads();
  int e0 = blk * EPB;
#pragma unroll
  for (int it = 0; it < EPB / 256; ++it) {
    int e = e0 + it * 256 + t;
    if (e < NEDGES) atomicAdd(&hist[((unsigned)edst[e]) >> 10], 1);
  }
  __syncthreads();
  if (t < NBUCK) blockHist[blk * NBUCK + t] = hist[t];
}

__global__ __launch_bounds__(512) void colscan(const int* __restrict__ blockHist,
                                               int* __restrict__ blockBaseCol,
                                               int* __restrict__ bucket_total) {
  __shared__ int s[512];
  int b = blockIdx.x, t = threadIdx.x;
  int v = (t < EBLK) ? blockHist[t * NBUCK + b] : 0;
  s[t] = v;
  __syncthreads();
  for (int off = 1; off < 512; off <<= 1) {
    int u = (t >= off) ? s[t - off] : 0;
    __syncthreads();
    s[t] += u;
    __syncthreads();
  }
  if (t < EBLK) blockBaseCol[b * EBLK + t] = s[t] - v;
  if (t == 511) bucket_total[b] = s[511];
}

__global__ __launch_bounds__(128) void bscan(const int* __restrict__ bucket_total,
                                             int* __restrict__ bucket_ptr) {
  __shared__ int s[128];
  int t = threadIdx.x;
  int v = (t < NBUCK) ? bucket_total[t] : 0;
  s[t] = v;
  __syncthreads();
  for (int off = 1; off < 128; off <<= 1) {
    int u = (t >= off) ? s[t - off] : 0;
    __syncthreads();
    s[t] += u;
    __syncthreads();
  }
  if (t < NBUCK) bucket_ptr[t] = s[t] - v;
  if (t == 127) bucket_ptr[NBUCK] = s[127];
}

// staging entry: (dst_local_10bits << 17) | src_17bits  (NNODES < 2^17)
__global__ __launch_bounds__(512) void bin_place(const int* __restrict__ esrc,
                                                 const int* __restrict__ edst,
                                                 const int* __restrict__ blockBaseCol,
                                                 const int* __restrict__ bucket_ptr,
                                                 unsigned* __restrict__ stagingG) {
  __shared__ int hist[NBUCK + 1], lbase[NBUCK + 1], lcur[NBUCK + 1], cbase[NBUCK];
  __shared__ int tmp[128];
  __shared__ uint2 st[EPB];
  int t = threadIdx.x, blk = blockIdx.x;
  if (t < NBUCK + 1) hist[t] = 0;
  __syncthreads();
  int e0 = blk * EPB;
#pragma unroll
  for (int it = 0; it < EPB / 512; ++it) {
    int e = e0 + it * 512 + t;
    int b = NBUCK;
    if (e < NEDGES) b = ((unsigned)edst[e]) >> 10;
    atomicAdd(&hist[b], 1);
  }
  __syncthreads();
  if (t < 128) tmp[t] = (t < NBUCK + 1) ? hist[t] : 0;
  __syncthreads();
  for (int off = 1; off < 128; off <<= 1) {
    int u = 0;
    if (t < 128 && t >= off) u = tmp[t - off];
    __syncthreads();
    if (t < 128) tmp[t] += u;
    __syncthreads();
  }
  if (t < NBUCK + 1) { int ex = tmp[t] - hist[t]; lbase[t] = ex; lcur[t] = ex; }
  if (t < NBUCK) cbase[t] = bucket_ptr[t] + blockBaseCol[t * EBLK + blk];
  __syncthreads();
#pragma unroll
  for (int it = 0; it < EPB / 512; ++it) {
    int e = e0 + it * 512 + t;
    unsigned s = 0, d = 0xFFFFFFFFu;
    if (e < NEDGES) { s = (unsigned)esrc[e]; d = (unsigned)edst[e]; }
    int b = (d == 0xFFFFFFFFu) ? NBUCK : (int)(d >> 10);
    int slot = atomicAdd(&lcur[b], 1);
    st[slot] = make_uint2(s, d);
  }
  __syncthreads();
  for (int i = t; i < EPB; i += 512) {
    uint2 ed = st[i];
    if (ed.y == 0xFFFFFFFFu) continue;
    int b = (int)(ed.y >> 10);
    stagingG[cbase[b] + (i - lbase[b])] = ((ed.y & 1023u) << 17) | ed.x;
  }
}

// fused: per-bucket degree histogram + LDS scan -> row_ptr, then scatter
__global__ __launch_bounds__(1024) void bucket_csr_fused(const unsigned* __restrict__ stagingG,
                                                         const int* __restrict__ bucket_ptr,
                                                         int* __restrict__ row_ptr,
                                                         int* __restrict__ colv) {
  __shared__ int dl[1024];
  __shared__ int cur[1024];
  int b = blockIdx.x, t = threadIdx.x;
  dl[t] = 0;
  __syncthreads();
  int s0 = bucket_ptr[b], s1 = bucket_ptr[b + 1];
  for (int j = s0 + t; j < s1; j += 1024)
    atomicAdd(&dl[stagingG[j] >> 17], 1);
  __syncthreads();
  int myDeg = dl[t];
  for (int off = 1; off < 1024; off <<= 1) {
    int u = (t >= off) ? dl[t - off] : 0;
    __syncthreads();
    dl[t] += u;
    __syncthreads();
  }
  int rp = s0 + dl[t] - myDeg;
  cur[t] = rp;
  int n = (b << 10) + t;
  if (n < NNODES) row_ptr[n] = rp;
  if (n == NNODES - 1) row_ptr[NNODES] = rp + myDeg;
  __syncthreads();
  for (int j = s0 + t; j < s1; j += 1024) {
    unsigned v = stagingG[j];
    int pos = atomicAdd(&cur[v >> 17], 1);
    colv[pos] = (int)(v & 0x1FFFFu);
  }
}

// ---------------- softmax aggregation: one wave per dst node -----------------
// fp8 payload (128B/row); weights broadcast via wave-private LDS ds_read_b64;
// gather unrolled 8-deep. Graph pooling fused as 2 atomicAdds per node.
__global__ __launch_bounds__(256) void aggregate(const unsigned short* __restrict__ hwb,
                                                 const float* __restrict__ a_s,
                                                 const float* __restrict__ a_d,
                                                 const int* __restrict__ row_ptr,
                                                 const int* __restrict__ colv,
                                                 const float* __restrict__ bias,
                                                 const int* __restrict__ batch,
                                                 float* __restrict__ reprs,
                                                 unsigned short* __restrict__ out) {
  __shared__ float2 wsh[256];           // 4 waves x 64 (w0,w1) entries
  int i = (blockIdx.x * 256 + threadIdx.x) >> 6;
  int lane = threadIdx.x & 63;
  if (i >= NNODES) return;
  i = __builtin_amdgcn_readfirstlane(i);
  int wbase = (threadIdx.x >> 6) * 64;

  float ad0 = a_d[2 * i], ad1 = a_d[2 * i + 1];
  int start = row_ptr[i], end = row_ptr[i + 1];
  int deg = end - start;
  float ws0 = __expf(lrelu(a_s[2 * i] + ad0));      // self edge
  float ws1 = __expf(lrelu(a_s[2 * i + 1] + ad1));

  int sl = 0; float w0l = 0.f, w1l = 0.f;
  if (lane < deg) {
    sl = colv[start + lane];
    float2 av = *reinterpret_cast<const float2*>(&a_s[2 * sl]);
    w0l = __expf(lrelu(av.x + ad0));
    w1l = __expf(lrelu(av.y + ad1));
  }
  wsh[wbase + lane] = make_float2(w0l, w1l);   // wave-private, no barrier
  float d0 = w0l, d1 = w1l;
  for (int o = 32; o; o >>= 1) { d0 += __shfl_xor(d0, o); d1 += __shfl_xor(d1, o); }
  float den0 = d0 + ws0, den1 = d1 + ws1;

  unsigned ps = hwb[(size_t)i * 64 + lane];
  f2v pv = pk_unpack_fp8(ps);
  float acc0 = ws0 * pv.x, acc1 = ws1 * pv.y;

  int dmin = deg < 64 ? deg : 64;
  int t = 0;
#define GSTEP(T)                                                               \
  {                                                                            \
    int s = __builtin_amdgcn_readlane(sl, (T));                                \
    unsigned q = hwb[(size_t)s * 64 + lane];                                   \
    float2 w = wsh[wbase + (T)];            /* ds_read_b64 broadcast */        \
    f2v xv = pk_unpack_fp8(q);                                                 \
    acc0 = fmaf(w.x, xv.x, acc0);                                              \
    acc1 = fmaf(w.y, xv.y, acc1);                                              \
  }
  for (; t + 8 <= dmin; t += 8) {
    GSTEP(t);     GSTEP(t + 1); GSTEP(t + 2); GSTEP(t + 3);
    GSTEP(t + 4); GSTEP(t + 5); GSTEP(t + 6); GSTEP(t + 7);
  }
  for (; t < dmin; ++t) { GSTEP(t); }
#undef GSTEP

  for (int j = start + 64; j < end; ++j) {   // rare overflow path (deg > 64)
    int s = colv[j];
    float2 av = *reinterpret_cast<const float2*>(&a_s[2 * s]);
    float w0 = __expf(lrelu(av.x + ad0));
    float w1 = __expf(lrelu(av.y + ad1));
    den0 += w0; den1 += w1;
    unsigned q = hwb[(size_t)s * 64 + lane];
    f2v xv = pk_unpack_fp8(q);
    acc0 = fmaf(w0, xv.x, acc0);
    acc1 = fmaf(w1, xv.y, acc1);
  }

  float r0 = fast_rcp(den0), r1 = fast_rcp(den1);
  float o0 = fmaxf(acc0 * r0 + bias[lane], 0.f);
  float o1 = fmaxf(acc1 * r1 + bias[64 + lane], 0.f);
  unsigned pk = cvt_pk_bf16(o0, o1);
  out[(size_t)i * 128 + lane]      = (unsigned short)pk;
  out[(size_t)i * 128 + 64 + lane] = (unsigned short)(pk >> 16);
  int g = batch[i];
  atomicAdd(&reprs[g * 128 + lane], o0);          // fused graph pooling
  atomicAdd(&reprs[g * 128 + 64 + lane], o1);
}

// ---------------- head MLP + log_softmax -------------------------------------
__global__ __launch_bounds__(128) void head_kernel(const float* __restrict__ reprs,
                                                   const float* __restrict__ pw1,
                                                   const float* __restrict__ pb1,
                                                   const float* __restrict__ pw2,
                                                   const float* __restrict__ pb2,
                                                   float* __restrict__ out) {
  __shared__ float r[128], t1[128], z[NCLS];
  int g = blockIdx.x, tid = threadIdx.x;
  r[tid] = reprs[g * 128 + tid];
  __syncthreads();
  float acc = pb1[tid];
  for (int k = 0; k < 128; ++k) acc = fmaf(r[k], pw1[k * 128 + tid], acc);
  t1[tid] = fmaxf(acc, 0.f);
  __syncthreads();
  if (tid < NCLS) {
    float zz = pb2[tid];
    for (int k = 0; k < 128; ++k) zz = fmaf(t1[k], pw2[k * NCLS + tid], zz);
    z[tid] = zz;
  }
  __syncthreads();
  if (tid == 0) {
    float mx = -1e30f;
    for (int c = 0; c < NCLS; ++c) mx = fmaxf(mx, z[c]);
    float s = 0.f;
    for (int c = 0; c < NCLS; ++c) s += expf(z[c] - mx);
    float ls = logf(s) + mx;
    for (int c = 0; c < NCLS; ++c) out[g * NCLS + c] = z[c] - ls;
  }
}

extern "C" void kernel_launch(void* const* d_in, const int* in_sizes, int n_in,
                              void* d_out, int out_size, void* d_ws, size_t ws_size,
                              hipStream_t stream) {
  const float* x     = (const float*)d_in[0];
  const int*   eidx  = (const int*)d_in[1];
  const int*   batch = (const int*)d_in[2];
  const float* pre_w = (const float*)d_in[3];
  const float* pre_b = (const float*)d_in[4];
  const float* w1    = (const float*)d_in[5];
  const float* asrc1 = (const float*)d_in[6];
  const float* adst1 = (const float*)d_in[7];
  const float* b1    = (const float*)d_in[8];
  const float* w2    = (const float*)d_in[9];
  const float* asrc2 = (const float*)d_in[10];
  const float* adst2 = (const float*)d_in[11];
  const float* b2    = (const float*)d_in[12];
  const float* pw1   = (const float*)d_in[13];
  const float* pb1   = (const float*)d_in[14];
  const float* pw2   = (const float*)d_in[15];
  const float* pb2   = (const float*)d_in[16];
  float* out = (float*)d_out;

  const int* esrc = eidx;
  const int* edst = eidx + NEDGES;

  char* wsp = (char*)d_ws;
  size_t off = 0;
  auto alloc = [&](size_t bytes) -> void* {
    void* p = wsp + off;
    off += (bytes + 255) & ~(size_t)255;
    return p;
  };
  unsigned short* hb  = (unsigned short*)alloc((size_t)NNODES * 128 * 2);
  unsigned short* hwb = (unsigned short*)alloc((size_t)NNODES * 64 * 2);   // fp8 pairs
  float* a_s         = (float*)alloc((size_t)NNODES * 2 * 4);
  float* a_d         = (float*)alloc((size_t)NNODES * 2 * 4);
  float* reprs       = (float*)alloc((size_t)NGRAPH * 128 * 4);
  int* row_ptr       = (int*)alloc(((size_t)NNODES + 1) * 4);
  int* colv          = (int*)alloc((size_t)NEDGES * 4);
  unsigned short* wt_pre = (unsigned short*)alloc((size_t)128 * FIN * 2);
  unsigned short* wt1    = (unsigned short*)alloc((size_t)128 * HDIM * 2);
  unsigned short* wt2    = (unsigned short*)alloc((size_t)128 * HDIM * 2);
  int* blockHist     = (int*)alloc((size_t)EBLK * NBUCK * 4);
  int* blockBaseCol  = (int*)alloc((size_t)NBUCK * EBLK * 4);
  int* bucket_total  = (int*)alloc(NBUCK * 4);
  int* bucket_ptr    = (int*)alloc((NBUCK + 1) * 4);
  unsigned* stagingG = (unsigned*)alloc((size_t)NEDGES * 4);

  int wb = NNODES / 4;             // wave-per-node kernels: 256 thr = 4 waves
  int gb = (NNODES + 63) / 64;     // 1563 GEMM blocks (64-row tiles)

  // one-shot weight conversion (bf16, transposed)
  convert_transpose<<<(FIN * 128 + 255) / 256, 256, 0, stream>>>(pre_w, wt_pre, FIN);
  convert_transpose<<<(HDIM * 128 + 255) / 256, 256, 0, stream>>>(w1, wt1, HDIM);
  convert_transpose<<<(HDIM * 128 + 255) / 256, 256, 0, stream>>>(w2, wt2, HDIM);

  // zeroed pooling accumulator (filled by fused atomics)
  hipMemsetAsync(reprs, 0, (size_t)NGRAPH * 128 * 4, stream);

  // bucketed CSR build (packed 4B staging; fused deg-scan + scatter)
  bin_count<<<EBLK, 256, 0, stream>>>(edst, blockHist);
  colscan<<<NBUCK, 512, 0, stream>>>(blockHist, blockBaseCol, bucket_total);
  bscan<<<1, 128, 0, stream>>>(bucket_total, bucket_ptr);
  bin_place<<<EBLK, 512, 0, stream>>>(esrc, edst, blockBaseCol, bucket_ptr, stagingG);
  bucket_csr_fused<<<NBUCK, 1024, 0, stream>>>(stagingG, bucket_ptr, row_ptr, colv);

  // pre layer: h0 = relu(x @ pre_w + pre_b)  (bf16 h; pooling fused)
  gemm_pipe<FIN, 0><<<gb, 256, 0, stream>>>(x, wt_pre, pre_b, hb, nullptr,
                                            nullptr, nullptr, nullptr, nullptr,
                                            batch, reprs, NNODES, 1);

  // GAT layer 1 (bf16 A; alpha fused into GEMM epilogue; fp8 value payload)
  gemm_pipe<HDIM, 1><<<gb, 256, 0, stream>>>(hb, wt1, nullptr, nullptr, hwb,
                                             asrc1, adst1, a_s, a_d,
                                             nullptr, nullptr, NNODES, 0);
  aggregate<<<wb, 256, 0, stream>>>(hwb, a_s, a_d, row_ptr, colv, b1, batch, reprs, hb);

  // GAT layer 2
  gemm_pipe<HDIM, 1><<<gb, 256, 0, stream>>>(hb, wt2, nullptr, nullptr, hwb,
                                             asrc2, adst2, a_s, a_d,
                                             nullptr, nullptr, NNODES, 0);
  aggregate<<<wb, 256, 0, stream>>>(hwb, a_s, a_d, row_ptr, colv, b2, batch, reprs, hb);

  // head
  head_kernel<<<NGRAPH, 128, 0, stream>>>(reprs, pw1, pb1, pw2, pb2, out);
}

// Round 9
// 466.034 us; speedup vs baseline: 1.9070x; 1.9070x over previous
//
#include <hip/hip_runtime.h>
#include <hip/hip_bf16.h>
#include <math.h>

#define NNODES 100000
#define NEDGES 1600000
#define FIN 256
#define HDIM 128
#define NGRAPH 128
#define NCLS 10
#define NEG 0.2f

#define NBUCK 98            // buckets of 1024 dst nodes
#define EPB 4096            // edges per bin_place block
#define EBLK ((NEDGES + EPB - 1) / EPB)   // 391

typedef short bf8 __attribute__((ext_vector_type(8)));
typedef float f4 __attribute__((ext_vector_type(4)));
typedef float f2v __attribute__((ext_vector_type(2)));

__device__ __forceinline__ float lrelu(float x) { return x > 0.f ? x : NEG * x; }

__device__ __forceinline__ unsigned short f2bf(float f) {
  union { float f; unsigned int u; } v; v.f = f;
  unsigned int r = v.u + 0x7fffu + ((v.u >> 16) & 1u);   // round-nearest-even
  return (unsigned short)(r >> 16);
}
__device__ __forceinline__ float bf2f(unsigned short u) {
  union { unsigned int u; float f; } v; v.u = ((unsigned int)u) << 16; return v.f;
}
__device__ __forceinline__ float fast_rcp(float x) {
  float r;
  asm("v_rcp_f32 %0, %1" : "=v"(r) : "v"(x));
  return r;
}
__device__ __forceinline__ unsigned cvt_pk_bf16(float lo, float hi) {
  unsigned r;
  asm("v_cvt_pk_bf16_f32 %0, %1, %2" : "=v"(r) : "v"(lo), "v"(hi));
  return r;
}
// fp8 e4m3 (OCP, gfx950 native) pack/unpack: value payload for the gather.
__device__ __forceinline__ unsigned short pk_fp8(float a, float b) {
  return (unsigned short)__builtin_amdgcn_cvt_pk_fp8_f32(a, b, 0, false);
}
// one-instruction unpack of both heads: v_cvt_pk_f32_fp8 (bytes 0,1 -> 2x f32)
__device__ __forceinline__ f2v pk_unpack_fp8(unsigned p) {
#if __has_builtin(__builtin_amdgcn_cvt_pk_f32_fp8)
  return __builtin_amdgcn_cvt_pk_f32_fp8((int)p, false);
#else
  f2v r;
  r.x = __builtin_amdgcn_cvt_f32_fp8(p, 0);
  r.y = __builtin_amdgcn_cvt_f32_fp8(p, 1);
  return r;
#endif
}
// direct global->LDS DMA, 16B/lane: dest = wave-uniform base + lane*16,
// global src is PER-LANE (pre-swizzled addresses, linear LDS dest).
__device__ __forceinline__ void gload16(const void* gp, void* lp) {
  __builtin_amdgcn_global_load_lds(
      (const __attribute__((address_space(1))) void*)gp,
      (__attribute__((address_space(3))) void*)lp, 16, 0, 0);
}

// ------- one-shot weight convert+transpose, all 3 matrices in ONE launch -----
// w[K][128] -> wt[128][K], bf16. Region split: [0,FIN*128) -> wt_pre,
// then HDIM*128 for wt1, then HDIM*128 for wt2.
__global__ __launch_bounds__(256) void convert_all(const float* __restrict__ pre_w,
                                                   const float* __restrict__ w1,
                                                   const float* __restrict__ w2,
                                                   unsigned short* __restrict__ wt_pre,
                                                   unsigned short* __restrict__ wt1,
                                                   unsigned short* __restrict__ wt2) {
  int i = blockIdx.x * 256 + threadIdx.x;
  if (i < FIN * 128) {
    int k = i >> 7, n = i & 127;
    wt_pre[n * FIN + k] = f2bf(pre_w[(size_t)k * 128 + n]);
  } else if (i < (FIN + HDIM) * 128) {
    int j = i - FIN * 128;
    int k = j >> 7, n = j & 127;
    wt1[n * HDIM + k] = f2bf(w1[(size_t)k * 128 + n]);
  } else if (i < (FIN + 2 * HDIM) * 128) {
    int j = i - (FIN + HDIM) * 128;
    int k = j >> 7, n = j & 127;
    wt2[n * HDIM + k] = f2bf(w2[(size_t)k * 128 + n]);
  }
}

// ---------------- MFMA GEMM: global_load_lds double-buffer, 64x128 tile ------
// Best measured GEMM (R7). R8's atomic-fused variant regressed 6x (12.8M
// atomics onto 16K addresses); reverted. Six structural variants (tile size,
// barrier count, staging path, DMA, per-wave vmcnt pipeline) all land 62-81us
// with every pipe ~95% idle -- the wall is not explained by any intra-kernel
// structure tried; this is the best of the family.
template<int K, int ABF16>
__global__ __launch_bounds__(256) void gemm_gll(const void* __restrict__ Av,
                                                const unsigned short* __restrict__ Bt,
                                                const float* __restrict__ bias,
                                                unsigned short* __restrict__ Cb,
                                                unsigned short* __restrict__ Cp,
                                                const float* __restrict__ a_src,
                                                const float* __restrict__ a_dst,
                                                float* __restrict__ o_as,
                                                float* __restrict__ o_ad,
                                                int M, int dorelu) {
  constexpr int ABUF = ABF16 ? 4096 : 8192;
  constexpr int SPAN = ABUF + 8192;
  __shared__ alignas(16) char lds[2 * SPAN];
  int tid = threadIdx.x;
  int wv = tid >> 6, lane = tid & 63;
  int quad = lane >> 4, m16 = lane & 15;
  int row0 = blockIdx.x * 64;
  int rA = row0 + wv * 16 + m16; if (rA > M - 1) rA = M - 1;
  int nB0 = wv * 16 + m16, nB1 = (4 + wv) * 16 + m16;

  const unsigned short* Ab = (const unsigned short*)Av;
  const float* Af = (const float*)Av;

  auto stage = [&](int buf, int kb) {
    char* base = lds + buf * SPAN;
    if (ABF16) {
      gload16(&Ab[(size_t)rA * K + kb + quad * 8], base + wv * 1024);
    } else {
      gload16(&Af[(size_t)rA * K + kb + quad * 8],     base + wv * 2048);
      gload16(&Af[(size_t)rA * K + kb + quad * 8 + 4], base + wv * 2048 + 1024);
    }
    char* bb = base + ABUF;
    gload16(&Bt[(size_t)nB0 * K + kb + quad * 8], bb + wv * 1024);
    gload16(&Bt[(size_t)nB1 * K + kb + quad * 8], bb + (4 + wv) * 1024);
  };

  f4 acc[8];
#pragma unroll
  for (int b = 0; b < 8; ++b) acc[b] = (f4){0.f, 0.f, 0.f, 0.f};

  stage(0, 0);
  int cur = 0;
#pragma unroll
  for (int kb = 0; kb < K; kb += 32) {
    __syncthreads();                       // drains stage(cur) + prev reads
    if (kb + 32 < K) stage(cur ^ 1, kb + 32);
    const char* base = lds + cur * SPAN;
    bf8 af;
    if (ABF16) {
      af = *(const bf8*)(base + wv * 1024 + lane * 16);
    } else {
      float4 x0 = *(const float4*)(base + wv * 2048 + lane * 16);
      float4 x1 = *(const float4*)(base + wv * 2048 + 1024 + lane * 16);
      union { bf8 v; unsigned u[4]; } r;
      r.u[0] = cvt_pk_bf16(x0.x, x0.y); r.u[1] = cvt_pk_bf16(x0.z, x0.w);
      r.u[2] = cvt_pk_bf16(x1.x, x1.y); r.u[3] = cvt_pk_bf16(x1.z, x1.w);
      af = r.v;
    }
    const char* bb = base + ABUF;
#pragma unroll
    for (int tn = 0; tn < 8; ++tn) {
      bf8 bm = *(const bf8*)(bb + tn * 1024 + lane * 16);
      acc[tn] = __builtin_amdgcn_mfma_f32_16x16x32_bf16(af, bm, acc[tn], 0, 0, 0);
    }
    cur ^= 1;
  }

  if (Cp) {
    if (a_src) {
      float aS[8], aD[8];
#pragma unroll
      for (int tn = 0; tn < 4; ++tn) {
        aS[tn]     = a_src[tn * 16 + m16];
        aS[tn + 4] = a_src[64 + tn * 16 + m16];
        aD[tn]     = a_dst[tn * 16 + m16];
        aD[tn + 4] = a_dst[64 + tn * 16 + m16];
      }
#pragma unroll
      for (int r = 0; r < 4; ++r) {
        int row = row0 + wv * 16 + quad * 4 + r;
        float ps0 = 0.f, ps1 = 0.f, pd0 = 0.f, pd1 = 0.f;
#pragma unroll
        for (int tn = 0; tn < 4; ++tn) {
          float v0 = acc[tn][r], v1 = acc[tn + 4][r];
          ps0 = fmaf(v0, aS[tn], ps0);
          ps1 = fmaf(v1, aS[tn + 4], ps1);
          pd0 = fmaf(v0, aD[tn], pd0);
          pd1 = fmaf(v1, aD[tn + 4], pd1);
        }
#pragma unroll
        for (int o = 8; o; o >>= 1) {
          ps0 += __shfl_xor(ps0, o); ps1 += __shfl_xor(ps1, o);
          pd0 += __shfl_xor(pd0, o); pd1 += __shfl_xor(pd1, o);
        }
        if (m16 == 0 && row < M) {
          o_as[2 * row] = ps0; o_as[2 * row + 1] = ps1;
          o_ad[2 * row] = pd0; o_ad[2 * row + 1] = pd1;
        }
      }
    }
#pragma unroll
    for (int tn = 0; tn < 4; ++tn)
#pragma unroll
      for (int r = 0; r < 4; ++r) {
        int row = row0 + wv * 16 + quad * 4 + r;
        if (row < M) {
          Cp[(size_t)row * 64 + tn * 16 + m16] = pk_fp8(acc[tn][r], acc[tn + 4][r]);
        }
      }
  } else {
#pragma unroll
    for (int tn = 0; tn < 8; ++tn) {
      float bv = bias ? bias[tn * 16 + m16] : 0.f;
#pragma unroll
      for (int r = 0; r < 4; ++r) {
        int row = row0 + wv * 16 + quad * 4 + r;
        if (row < M) {
          float v = acc[tn][r] + bv;
          if (dorelu) v = fmaxf(v, 0.f);
          Cb[(size_t)row * 128 + tn * 16 + m16] = f2bf(v);
        }
      }
    }
  }
}

// ---------------- graph boundaries (batch is sorted) -------------------------
__global__ void find_starts(const int* __restrict__ batch, int* __restrict__ gstart) {
  int g = threadIdx.x;
  if (g > NGRAPH) return;
  if (g == NGRAPH) { gstart[g] = NNODES; return; }
  int lo = 0, hi = NNODES;
  while (lo < hi) { int mid = (lo + hi) >> 1; if (batch[mid] < g) lo = mid + 1; else hi = mid; }
  gstart[g] = lo;
}

// ======== CSR build, bucketed two-phase (no random global atomics) ==========
__global__ __launch_bounds__(256) void bin_count(const int* __restrict__ edst,
                                                 int* __restrict__ blockHist) {
  __shared__ int hist[NBUCK];
  int t = threadIdx.x, blk = blockIdx.x;
  if (t < NBUCK) hist[t] = 0;
  __syncthreads();
  int e0 = blk * EPB;
#pragma unroll
  for (int it = 0; it < EPB / 256; ++it) {
    int e = e0 + it * 256 + t;
    if (e < NEDGES) atomicAdd(&hist[((unsigned)edst[e]) >> 10], 1);
  }
  __syncthreads();
  if (t < NBUCK) blockHist[blk * NBUCK + t] = hist[t];
}

__global__ __launch_bounds__(512) void colscan(const int* __restrict__ blockHist,
                                               int* __restrict__ blockBaseCol,
                                               int* __restrict__ bucket_total) {
  __shared__ int s[512];
  int b = blockIdx.x, t = threadIdx.x;
  int v = (t < EBLK) ? blockHist[t * NBUCK + b] : 0;
  s[t] = v;
  __syncthreads();
  for (int off = 1; off < 512; off <<= 1) {
    int u = (t >= off) ? s[t - off] : 0;
    __syncthreads();
    s[t] += u;
    __syncthreads();
  }
  if (t < EBLK) blockBaseCol[b * EBLK + t] = s[t] - v;
  if (t == 511) bucket_total[b] = s[511];
}

__global__ __launch_bounds__(128) void bscan(const int* __restrict__ bucket_total,
                                             int* __restrict__ bucket_ptr) {
  __shared__ int s[128];
  int t = threadIdx.x;
  int v = (t < NBUCK) ? bucket_total[t] : 0;
  s[t] = v;
  __syncthreads();
  for (int off = 1; off < 128; off <<= 1) {
    int u = (t >= off) ? s[t - off] : 0;
    __syncthreads();
    s[t] += u;
    __syncthreads();
  }
  if (t < NBUCK) bucket_ptr[t] = s[t] - v;
  if (t == 127) bucket_ptr[NBUCK] = s[127];
}

// staging entry: (dst_local_10bits << 17) | src_17bits  (NNODES < 2^17)
__global__ __launch_bounds__(512) void bin_place(const int* __restrict__ esrc,
                                                 const int* __restrict__ edst,
                                                 const int* __restrict__ blockBaseCol,
                                                 const int* __restrict__ bucket_ptr,
                                                 unsigned* __restrict__ stagingG) {
  __shared__ int hist[NBUCK + 1], lbase[NBUCK + 1], lcur[NBUCK + 1], cbase[NBUCK];
  __shared__ int tmp[128];
  __shared__ uint2 st[EPB];
  int t = threadIdx.x, blk = blockIdx.x;
  if (t < NBUCK + 1) hist[t] = 0;
  __syncthreads();
  int e0 = blk * EPB;
#pragma unroll
  for (int it = 0; it < EPB / 512; ++it) {
    int e = e0 + it * 512 + t;
    int b = NBUCK;
    if (e < NEDGES) b = ((unsigned)edst[e]) >> 10;
    atomicAdd(&hist[b], 1);
  }
  __syncthreads();
  if (t < 128) tmp[t] = (t < NBUCK + 1) ? hist[t] : 0;
  __syncthreads();
  for (int off = 1; off < 128; off <<= 1) {
    int u = 0;
    if (t < 128 && t >= off) u = tmp[t - off];
    __syncthreads();
    if (t < 128) tmp[t] += u;
    __syncthreads();
  }
  if (t < NBUCK + 1) { int ex = tmp[t] - hist[t]; lbase[t] = ex; lcur[t] = ex; }
  if (t < NBUCK) cbase[t] = bucket_ptr[t] + blockBaseCol[t * EBLK + blk];
  __syncthreads();
#pragma unroll
  for (int it = 0; it < EPB / 512; ++it) {
    int e = e0 + it * 512 + t;
    unsigned s = 0, d = 0xFFFFFFFFu;
    if (e < NEDGES) { s = (unsigned)esrc[e]; d = (unsigned)edst[e]; }
    int b = (d == 0xFFFFFFFFu) ? NBUCK : (int)(d >> 10);
    int slot = atomicAdd(&lcur[b], 1);
    st[slot] = make_uint2(s, d);
  }
  __syncthreads();
  for (int i = t; i < EPB; i += 512) {
    uint2 ed = st[i];
    if (ed.y == 0xFFFFFFFFu) continue;
    int b = (int)(ed.y >> 10);
    stagingG[cbase[b] + (i - lbase[b])] = ((ed.y & 1023u) << 17) | ed.x;
  }
}

// fused: per-bucket degree histogram + LDS scan -> row_ptr, then scatter
__global__ __launch_bounds__(1024) void bucket_csr_fused(const unsigned* __restrict__ stagingG,
                                                         const int* __restrict__ bucket_ptr,
                                                         int* __restrict__ row_ptr,
                                                         int* __restrict__ colv) {
  __shared__ int dl[1024];
  __shared__ int cur[1024];
  int b = blockIdx.x, t = threadIdx.x;
  dl[t] = 0;
  __syncthreads();
  int s0 = bucket_ptr[b], s1 = bucket_ptr[b + 1];
  for (int j = s0 + t; j < s1; j += 1024)
    atomicAdd(&dl[stagingG[j] >> 17], 1);
  __syncthreads();
  int myDeg = dl[t];
  for (int off = 1; off < 1024; off <<= 1) {
    int u = (t >= off) ? dl[t - off] : 0;
    __syncthreads();
    dl[t] += u;
    __syncthreads();
  }
  int rp = s0 + dl[t] - myDeg;
  cur[t] = rp;
  int n = (b << 10) + t;
  if (n < NNODES) row_ptr[n] = rp;
  if (n == NNODES - 1) row_ptr[NNODES] = rp + myDeg;
  __syncthreads();
  for (int j = s0 + t; j < s1; j += 1024) {
    unsigned v = stagingG[j];
    int pos = atomicAdd(&cur[v >> 17], 1);
    colv[pos] = (int)(v & 0x1FFFFu);
  }
}

// ---------------- softmax aggregation: one wave per dst node -----------------
// fp8 payload (128B/row); weights broadcast via wave-private LDS ds_read_b64;
// both heads unpacked with one v_cvt_pk_f32_fp8; gather unrolled 8-deep.
__global__ __launch_bounds__(256) void aggregate(const unsigned short* __restrict__ hwb,
                                                 const float* __restrict__ a_s,
                                                 const float* __restrict__ a_d,
                                                 const int* __restrict__ row_ptr,
                                                 const int* __restrict__ colv,
                                                 const float* __restrict__ bias,
                                                 unsigned short* __restrict__ out) {
  __shared__ float2 wsh[256];           // 4 waves x 64 (w0,w1) entries
  int i = (blockIdx.x * 256 + threadIdx.x) >> 6;
  int lane = threadIdx.x & 63;
  if (i >= NNODES) return;
  i = __builtin_amdgcn_readfirstlane(i);
  int wbase = (threadIdx.x >> 6) * 64;

  float ad0 = a_d[2 * i], ad1 = a_d[2 * i + 1];
  int start = row_ptr[i], end = row_ptr[i + 1];
  int deg = end - start;
  float ws0 = __expf(lrelu(a_s[2 * i] + ad0));      // self edge
  float ws1 = __expf(lrelu(a_s[2 * i + 1] + ad1));

  int sl = 0; float w0l = 0.f, w1l = 0.f;
  if (lane < deg) {
    sl = colv[start + lane];
    float2 av = *reinterpret_cast<const float2*>(&a_s[2 * sl]);
    w0l = __expf(lrelu(av.x + ad0));
    w1l = __expf(lrelu(av.y + ad1));
  }
  wsh[wbase + lane] = make_float2(w0l, w1l);   // wave-private, no barrier
  float d0 = w0l, d1 = w1l;
  for (int o = 32; o; o >>= 1) { d0 += __shfl_xor(d0, o); d1 += __shfl_xor(d1, o); }
  float den0 = d0 + ws0, den1 = d1 + ws1;

  unsigned ps = hwb[(size_t)i * 64 + lane];
  f2v pv = pk_unpack_fp8(ps);
  float acc0 = ws0 * pv.x, acc1 = ws1 * pv.y;

  int dmin = deg < 64 ? deg : 64;
  int t = 0;
#define GSTEP(T)                                                               \
  {                                                                            \
    int s = __builtin_amdgcn_readlane(sl, (T));                                \
    unsigned q = hwb[(size_t)s * 64 + lane];                                   \
    float2 w = wsh[wbase + (T)];            /* ds_read_b64 broadcast */        \
    f2v xv = pk_unpack_fp8(q);                                                 \
    acc0 = fmaf(w.x, xv.x, acc0);                                              \
    acc1 = fmaf(w.y, xv.y, acc1);                                              \
  }
  for (; t + 8 <= dmin; t += 8) {
    GSTEP(t);     GSTEP(t + 1); GSTEP(t + 2); GSTEP(t + 3);
    GSTEP(t + 4); GSTEP(t + 5); GSTEP(t + 6); GSTEP(t + 7);
  }
  for (; t < dmin; ++t) { GSTEP(t); }
#undef GSTEP

  for (int j = start + 64; j < end; ++j) {   // rare overflow path (deg > 64)
    int s = colv[j];
    float2 av = *reinterpret_cast<const float2*>(&a_s[2 * s]);
    float w0 = __expf(lrelu(av.x + ad0));
    float w1 = __expf(lrelu(av.y + ad1));
    den0 += w0; den1 += w1;
    unsigned q = hwb[(size_t)s * 64 + lane];
    f2v xv = pk_unpack_fp8(q);
    acc0 = fmaf(w0, xv.x, acc0);
    acc1 = fmaf(w1, xv.y, acc1);
  }

  float r0 = fast_rcp(den0), r1 = fast_rcp(den1);
  float o0 = fmaxf(acc0 * r0 + bias[lane], 0.f);
  float o1 = fmaxf(acc1 * r1 + bias[64 + lane], 0.f);
  unsigned pk = cvt_pk_bf16(o0, o1);
  out[(size_t)i * 128 + lane]      = (unsigned short)pk;
  out[(size_t)i * 128 + 64 + lane] = (unsigned short)(pk >> 16);
}

// ---------------- per-graph pooling, node-parallel (bf16 input) --------------
#define SEG_CHUNK 128
__global__ __launch_bounds__(128) void seg_sum_fast(const unsigned short* __restrict__ h,
                                                    const int* __restrict__ batch,
                                                    const int* __restrict__ gstart,
                                                    float* __restrict__ reprs) {
  int n0 = blockIdx.x * SEG_CHUNK;
  if (n0 >= NNODES) return;
  int nend = n0 + SEG_CHUNK; if (nend > NNODES) nend = NNODES;
  int tid = threadIdx.x;
  int r = n0;
  while (r < nend) {
    int g = batch[r];
    int segend = gstart[g + 1]; if (segend > nend) segend = nend;
    float a0 = 0.f, a1 = 0.f, a2 = 0.f, a3 = 0.f;
    for (; r + 3 < segend; r += 4) {
      a0 += bf2f(h[(size_t)r * 128 + tid]);
      a1 += bf2f(h[(size_t)(r + 1) * 128 + tid]);
      a2 += bf2f(h[(size_t)(r + 2) * 128 + tid]);
      a3 += bf2f(h[(size_t)(r + 3) * 128 + tid]);
    }
    for (; r < segend; ++r) a0 += bf2f(h[(size_t)r * 128 + tid]);
    atomicAdd(&reprs[g * 128 + tid], (a0 + a1) + (a2 + a3));
  }
}

// ---------------- head MLP + log_softmax -------------------------------------
__global__ __launch_bounds__(128) void head_kernel(const float* __restrict__ reprs,
                                                   const float* __restrict__ pw1,
                                                   const float* __restrict__ pb1,
                                                   const float* __restrict__ pw2,
                                                   const float* __restrict__ pb2,
                                                   float* __restrict__ out) {
  __shared__ float r[128], t1[128], z[NCLS];
  int g = blockIdx.x, tid = threadIdx.x;
  r[tid] = reprs[g * 128 + tid];
  __syncthreads();
  float acc = pb1[tid];
  for (int k = 0; k < 128; ++k) acc = fmaf(r[k], pw1[k * 128 + tid], acc);
  t1[tid] = fmaxf(acc, 0.f);
  __syncthreads();
  if (tid < NCLS) {
    float zz = pb2[tid];
    for (int k = 0; k < 128; ++k) zz = fmaf(t1[k], pw2[k * NCLS + tid], zz);
    z[tid] = zz;
  }
  __syncthreads();
  if (tid == 0) {
    float mx = -1e30f;
    for (int c = 0; c < NCLS; ++c) mx = fmaxf(mx, z[c]);
    float s = 0.f;
    for (int c = 0; c < NCLS; ++c) s += expf(z[c] - mx);
    float ls = logf(s) + mx;
    for (int c = 0; c < NCLS; ++c) out[g * NCLS + c] = z[c] - ls;
  }
}

extern "C" void kernel_launch(void* const* d_in, const int* in_sizes, int n_in,
                              void* d_out, int out_size, void* d_ws, size_t ws_size,
                              hipStream_t stream) {
  const float* x     = (const float*)d_in[0];
  const int*   eidx  = (const int*)d_in[1];
  const int*   batch = (const int*)d_in[2];
  const float* pre_w = (const float*)d_in[3];
  const float* pre_b = (const float*)d_in[4];
  const float* w1    = (const float*)d_in[5];
  const float* asrc1 = (const float*)d_in[6];
  const float* adst1 = (const float*)d_in[7];
  const float* b1    = (const float*)d_in[8];
  const float* w2    = (const float*)d_in[9];
  const float* asrc2 = (const float*)d_in[10];
  const float* adst2 = (const float*)d_in[11];
  const float* b2    = (const float*)d_in[12];
  const float* pw1   = (const float*)d_in[13];
  const float* pb1   = (const float*)d_in[14];
  const float* pw2   = (const float*)d_in[15];
  const float* pb2   = (const float*)d_in[16];
  float* out = (float*)d_out;

  const int* esrc = eidx;
  const int* edst = eidx + NEDGES;

  char* wsp = (char*)d_ws;
  size_t off = 0;
  auto alloc = [&](size_t bytes) -> void* {
    void* p = wsp + off;
    off += (bytes + 255) & ~(size_t)255;
    return p;
  };
  unsigned short* hb  = (unsigned short*)alloc((size_t)NNODES * 128 * 2);
  unsigned short* hwb = (unsigned short*)alloc((size_t)NNODES * 64 * 2);   // fp8 pairs
  float* a_s         = (float*)alloc((size_t)NNODES * 2 * 4);
  float* a_d         = (float*)alloc((size_t)NNODES * 2 * 4);
  float* reprs       = (float*)alloc((size_t)NGRAPH * 128 * 4);
  int* gstart        = (int*)alloc((NGRAPH + 1) * 4);
  int* row_ptr       = (int*)alloc(((size_t)NNODES + 1) * 4);
  int* colv          = (int*)alloc((size_t)NEDGES * 4);
  unsigned short* wt_pre = (unsigned short*)alloc((size_t)128 * FIN * 2);
  unsigned short* wt1    = (unsigned short*)alloc((size_t)128 * HDIM * 2);
  unsigned short* wt2    = (unsigned short*)alloc((size_t)128 * HDIM * 2);
  int* blockHist     = (int*)alloc((size_t)EBLK * NBUCK * 4);
  int* blockBaseCol  = (int*)alloc((size_t)NBUCK * EBLK * 4);
  int* bucket_total  = (int*)alloc(NBUCK * 4);
  int* bucket_ptr    = (int*)alloc((NBUCK + 1) * 4);
  unsigned* stagingG = (unsigned*)alloc((size_t)NEDGES * 4);

  int wb = NNODES / 4;             // wave-per-node kernels: 256 thr = 4 waves
  int sb = (NNODES + SEG_CHUNK - 1) / SEG_CHUNK;
  int gb = (NNODES + 63) / 64;     // 1563 GEMM blocks (64-row tiles)

  // one-shot weight conversion (bf16, transposed) -- single fused launch
  convert_all<<<((FIN + 2 * HDIM) * 128 + 255) / 256, 256, 0, stream>>>(
      pre_w, w1, w2, wt_pre, wt1, wt2);

  // graph boundaries + zeroed pooling accumulator
  hipMemsetAsync(reprs, 0, (size_t)NGRAPH * 128 * 4, stream);
  find_starts<<<1, 256, 0, stream>>>(batch, gstart);

  // bucketed CSR build (packed 4B staging; fused deg-scan + scatter)
  bin_count<<<EBLK, 256, 0, stream>>>(edst, blockHist);
  colscan<<<NBUCK, 512, 0, stream>>>(blockHist, blockBaseCol, bucket_total);
  bscan<<<1, 128, 0, stream>>>(bucket_total, bucket_ptr);
  bin_place<<<EBLK, 512, 0, stream>>>(esrc, edst, blockBaseCol, bucket_ptr, stagingG);
  bucket_csr_fused<<<NBUCK, 1024, 0, stream>>>(stagingG, bucket_ptr, row_ptr, colv);

  // pre layer: h0 = relu(x @ pre_w + pre_b)  (bf16 h)
  gemm_gll<FIN, 0><<<gb, 256, 0, stream>>>(x, wt_pre, pre_b, hb, nullptr,
                                           nullptr, nullptr, nullptr, nullptr, NNODES, 1);
  seg_sum_fast<<<sb, 128, 0, stream>>>(hb, batch, gstart, reprs);

  // GAT layer 1 (bf16 A; alpha fused into GEMM epilogue; fp8 value payload)
  gemm_gll<HDIM, 1><<<gb, 256, 0, stream>>>(hb, wt1, nullptr, nullptr, hwb,
                                            asrc1, adst1, a_s, a_d, NNODES, 0);
  aggregate<<<wb, 256, 0, stream>>>(hwb, a_s, a_d, row_ptr, colv, b1, hb);
  seg_sum_fast<<<sb, 128, 0, stream>>>(hb, batch, gstart, reprs);

  // GAT layer 2
  gemm_gll<HDIM, 1><<<gb, 256, 0, stream>>>(hb, wt2, nullptr, nullptr, hwb,
                                            asrc2, adst2, a_s, a_d, NNODES, 0);
  aggregate<<<wb, 256, 0, stream>>>(hwb, a_s, a_d, row_ptr, colv, b2, hb);
  seg_sum_fast<<<sb, 128, 0, stream>>>(hb, batch, gstart, reprs);

  // head
  head_kernel<<<NGRAPH, 128, 0, stream>>>(reprs, pw1, pb1, pw2, pb2, out);
}

// Round 11
// 462.813 us; speedup vs baseline: 1.9202x; 1.0070x over previous
//
#include <hip/hip_runtime.h>
#include <hip/hip_bf16.h>
#include <math.h>

#define NNODES 100000
#define NEDGES 1600000
#define FIN 256
#define HDIM 128
#define NGRAPH 128
#define NCLS 10
#define NEG 0.2f

#define NBUCK 98            // buckets of 1024 dst nodes
#define EPB 4096            // edges per bin_place block
#define EBLK ((NEDGES + EPB - 1) / EPB)   // 391

typedef short bf8 __attribute__((ext_vector_type(8)));
typedef float f4 __attribute__((ext_vector_type(4)));
typedef float f2v __attribute__((ext_vector_type(2)));

__device__ __forceinline__ float lrelu(float x) { return x > 0.f ? x : NEG * x; }

__device__ __forceinline__ unsigned short f2bf(float f) {
  union { float f; unsigned int u; } v; v.f = f;
  unsigned int r = v.u + 0x7fffu + ((v.u >> 16) & 1u);   // round-nearest-even
  return (unsigned short)(r >> 16);
}
__device__ __forceinline__ float bf_lo(unsigned int p) {
  union { unsigned int u; float f; } v; v.u = p << 16; return v.f;
}
__device__ __forceinline__ float bf_hi(unsigned int p) {
  union { unsigned int u; float f; } v; v.u = p & 0xffff0000u; return v.f;
}
__device__ __forceinline__ float fast_rcp(float x) {
  float r;
  asm("v_rcp_f32 %0, %1" : "=v"(r) : "v"(x));
  return r;
}
__device__ __forceinline__ unsigned cvt_pk_bf16(float lo, float hi) {
  unsigned r;
  asm("v_cvt_pk_bf16_f32 %0, %1, %2" : "=v"(r) : "v"(lo), "v"(hi));
  return r;
}
// fp8 e4m3 (OCP, gfx950 native) pack/unpack: value payload for the gather.
__device__ __forceinline__ unsigned short pk_fp8(float a, float b) {
  return (unsigned short)__builtin_amdgcn_cvt_pk_fp8_f32(a, b, 0, false);
}
// one-instruction unpack of both heads: v_cvt_pk_f32_fp8 (bytes 0,1 -> 2x f32)
__device__ __forceinline__ f2v pk_unpack_fp8(unsigned p) {
#if __has_builtin(__builtin_amdgcn_cvt_pk_f32_fp8)
  return __builtin_amdgcn_cvt_pk_f32_fp8((int)p, false);
#else
  f2v r;
  r.x = __builtin_amdgcn_cvt_f32_fp8(p, 0);
  r.y = __builtin_amdgcn_cvt_f32_fp8(p, 1);
  return r;
#endif
}
// direct global->LDS DMA, 16B/lane: dest = wave-uniform base + lane*16,
// global src is PER-LANE (pre-swizzled addresses, linear LDS dest).
__device__ __forceinline__ void gload16(const void* gp, void* lp) {
  __builtin_amdgcn_global_load_lds(
      (const __attribute__((address_space(1))) void*)gp,
      (__attribute__((address_space(3))) void*)lp, 16, 0, 0);
}

// ------- one-shot weight convert+transpose (3 matrices) + find_starts -------
// w[K][128] -> wt[128][K], bf16. Region split: [0,FIN*128) -> wt_pre,
// then HDIM*128 for wt1, then HDIM*128 for wt2. Block 0's threads <=NGRAPH
// additionally compute per-graph start offsets (batch is sorted).
__global__ __launch_bounds__(256) void convert_all(const float* __restrict__ pre_w,
                                                   const float* __restrict__ w1,
                                                   const float* __restrict__ w2,
                                                   unsigned short* __restrict__ wt_pre,
                                                   unsigned short* __restrict__ wt1,
                                                   unsigned short* __restrict__ wt2,
                                                   const int* __restrict__ batch,
                                                   int* __restrict__ gstart) {
  if (blockIdx.x == 0 && threadIdx.x <= NGRAPH) {
    int g = threadIdx.x;
    if (g == NGRAPH) {
      gstart[g] = NNODES;
    } else {
      int lo = 0, hi = NNODES;
      while (lo < hi) { int mid = (lo + hi) >> 1; if (batch[mid] < g) lo = mid + 1; else hi = mid; }
      gstart[g] = lo;
    }
  }
  int i = blockIdx.x * 256 + threadIdx.x;
  if (i < FIN * 128) {
    int k = i >> 7, n = i & 127;
    wt_pre[n * FIN + k] = f2bf(pre_w[(size_t)k * 128 + n]);
  } else if (i < (FIN + HDIM) * 128) {
    int j = i - FIN * 128;
    int k = j >> 7, n = j & 127;
    wt1[n * HDIM + k] = f2bf(w1[(size_t)k * 128 + n]);
  } else if (i < (FIN + 2 * HDIM) * 128) {
    int j = i - (FIN + HDIM) * 128;
    int k = j >> 7, n = j & 127;
    wt2[n * HDIM + k] = f2bf(w2[(size_t)k * 128 + n]);
  }
}

// ---------------- MFMA GEMM: global_load_lds double-buffer, 64x128 tile ------
// Best measured GEMM (R7/R9). Six structural variants (tile size, barrier
// count, staging path, DMA, per-wave vmcnt pipeline) all land 62-81us with
// every pipe ~95% idle -- the wall did not yield to any intra-kernel
// structure tried; this is the best of the family. Do not rewrite.
template<int K, int ABF16>
__global__ __launch_bounds__(256) void gemm_gll(const void* __restrict__ Av,
                                                const unsigned short* __restrict__ Bt,
                                                const float* __restrict__ bias,
                                                unsigned short* __restrict__ Cb,
                                                unsigned short* __restrict__ Cp,
                                                const float* __restrict__ a_src,
                                                const float* __restrict__ a_dst,
                                                float* __restrict__ o_as,
                                                float* __restrict__ o_ad,
                                                int M, int dorelu) {
  constexpr int ABUF = ABF16 ? 4096 : 8192;
  constexpr int SPAN = ABUF + 8192;
  __shared__ alignas(16) char lds[2 * SPAN];
  int tid = threadIdx.x;
  int wv = tid >> 6, lane = tid & 63;
  int quad = lane >> 4, m16 = lane & 15;
  int row0 = blockIdx.x * 64;
  int rA = row0 + wv * 16 + m16; if (rA > M - 1) rA = M - 1;
  int nB0 = wv * 16 + m16, nB1 = (4 + wv) * 16 + m16;

  const unsigned short* Ab = (const unsigned short*)Av;
  const float* Af = (const float*)Av;

  auto stage = [&](int buf, int kb) {
    char* base = lds + buf * SPAN;
    if (ABF16) {
      gload16(&Ab[(size_t)rA * K + kb + quad * 8], base + wv * 1024);
    } else {
      gload16(&Af[(size_t)rA * K + kb + quad * 8],     base + wv * 2048);
      gload16(&Af[(size_t)rA * K + kb + quad * 8 + 4], base + wv * 2048 + 1024);
    }
    char* bb = base + ABUF;
    gload16(&Bt[(size_t)nB0 * K + kb + quad * 8], bb + wv * 1024);
    gload16(&Bt[(size_t)nB1 * K + kb + quad * 8], bb + (4 + wv) * 1024);
  };

  f4 acc[8];
#pragma unroll
  for (int b = 0; b < 8; ++b) acc[b] = (f4){0.f, 0.f, 0.f, 0.f};

  stage(0, 0);
  int cur = 0;
#pragma unroll
  for (int kb = 0; kb < K; kb += 32) {
    __syncthreads();                       // drains stage(cur) + prev reads
    if (kb + 32 < K) stage(cur ^ 1, kb + 32);
    const char* base = lds + cur * SPAN;
    bf8 af;
    if (ABF16) {
      af = *(const bf8*)(base + wv * 1024 + lane * 16);
    } else {
      float4 x0 = *(const float4*)(base + wv * 2048 + lane * 16);
      float4 x1 = *(const float4*)(base + wv * 2048 + 1024 + lane * 16);
      union { bf8 v; unsigned u[4]; } r;
      r.u[0] = cvt_pk_bf16(x0.x, x0.y); r.u[1] = cvt_pk_bf16(x0.z, x0.w);
      r.u[2] = cvt_pk_bf16(x1.x, x1.y); r.u[3] = cvt_pk_bf16(x1.z, x1.w);
      af = r.v;
    }
    const char* bb = base + ABUF;
#pragma unroll
    for (int tn = 0; tn < 8; ++tn) {
      bf8 bm = *(const bf8*)(bb + tn * 1024 + lane * 16);
      acc[tn] = __builtin_amdgcn_mfma_f32_16x16x32_bf16(af, bm, acc[tn], 0, 0, 0);
    }
    cur ^= 1;
  }

  if (Cp) {
    if (a_src) {
      float aS[8], aD[8];
#pragma unroll
      for (int tn = 0; tn < 4; ++tn) {
        aS[tn]     = a_src[tn * 16 + m16];
        aS[tn + 4] = a_src[64 + tn * 16 + m16];
        aD[tn]     = a_dst[tn * 16 + m16];
        aD[tn + 4] = a_dst[64 + tn * 16 + m16];
      }
#pragma unroll
      for (int r = 0; r < 4; ++r) {
        int row = row0 + wv * 16 + quad * 4 + r;
        float ps0 = 0.f, ps1 = 0.f, pd0 = 0.f, pd1 = 0.f;
#pragma unroll
        for (int tn = 0; tn < 4; ++tn) {
          float v0 = acc[tn][r], v1 = acc[tn + 4][r];
          ps0 = fmaf(v0, aS[tn], ps0);
          ps1 = fmaf(v1, aS[tn + 4], ps1);
          pd0 = fmaf(v0, aD[tn], pd0);
          pd1 = fmaf(v1, aD[tn + 4], pd1);
        }
#pragma unroll
        for (int o = 8; o; o >>= 1) {
          ps0 += __shfl_xor(ps0, o); ps1 += __shfl_xor(ps1, o);
          pd0 += __shfl_xor(pd0, o); pd1 += __shfl_xor(pd1, o);
        }
        if (m16 == 0 && row < M) {
          o_as[2 * row] = ps0; o_as[2 * row + 1] = ps1;
          o_ad[2 * row] = pd0; o_ad[2 * row + 1] = pd1;
        }
      }
    }
#pragma unroll
    for (int tn = 0; tn < 4; ++tn)
#pragma unroll
      for (int r = 0; r < 4; ++r) {
        int row = row0 + wv * 16 + quad * 4 + r;
        if (row < M) {
          Cp[(size_t)row * 64 + tn * 16 + m16] = pk_fp8(acc[tn][r], acc[tn + 4][r]);
        }
      }
  } else {
#pragma unroll
    for (int tn = 0; tn < 8; ++tn) {
      float bv = bias ? bias[tn * 16 + m16] : 0.f;
#pragma unroll
      for (int r = 0; r < 4; ++r) {
        int row = row0 + wv * 16 + quad * 4 + r;
        if (row < M) {
          float v = acc[tn][r] + bv;
          if (dorelu) v = fmaxf(v, 0.f);
          Cb[(size_t)row * 128 + tn * 16 + m16] = f2bf(v);
        }
      }
    }
  }
}

// ======== CSR build, bucketed two-phase (no random global atomics) ==========
__global__ __launch_bounds__(256) void bin_count(const int* __restrict__ edst,
                                                 int* __restrict__ blockHist) {
  __shared__ int hist[NBUCK];
  int t = threadIdx.x, blk = blockIdx.x;
  if (t < NBUCK) hist[t] = 0;
  __syncthreads();
  int e0 = blk * EPB;
#pragma unroll
  for (int it = 0; it < EPB / 256; ++it) {
    int e = e0 + it * 256 + t;
    if (e < NEDGES) atomicAdd(&hist[((unsigned)edst[e]) >> 10], 1);
  }
  __syncthreads();
  if (t < NBUCK) blockHist[blk * NBUCK + t] = hist[t];
}

__global__ __launch_bounds__(512) void colscan(const int* __restrict__ blockHist,
                                               int* __restrict__ blockBaseCol,
                                               int* __restrict__ bucket_total) {
  __shared__ int s[512];
  int b = blockIdx.x, t = threadIdx.x;
  int v = (t < EBLK) ? blockHist[t * NBUCK + b] : 0;
  s[t] = v;
  __syncthreads();
  for (int off = 1; off < 512; off <<= 1) {
    int u = (t >= off) ? s[t - off] : 0;
    __syncthreads();
    s[t] += u;
    __syncthreads();
  }
  if (t < EBLK) blockBaseCol[b * EBLK + t] = s[t] - v;
  if (t == 511) bucket_total[b] = s[511];
}

__global__ __launch_bounds__(128) void bscan(const int* __restrict__ bucket_total,
                                             int* __restrict__ bucket_ptr) {
  __shared__ int s[128];
  int t = threadIdx.x;
  int v = (t < NBUCK) ? bucket_total[t] : 0;
  s[t] = v;
  __syncthreads();
  for (int off = 1; off < 128; off <<= 1) {
    int u = (t >= off) ? s[t - off] : 0;
    __syncthreads();
    s[t] += u;
    __syncthreads();
  }
  if (t < NBUCK) bucket_ptr[t] = s[t] - v;
  if (t == 127) bucket_ptr[NBUCK] = s[127];
}

// staging entry: (dst_local_10bits << 17) | src_17bits  (NNODES < 2^17)
__global__ __launch_bounds__(512) void bin_place(const int* __restrict__ esrc,
                                                 const int* __restrict__ edst,
                                                 const int* __restrict__ blockBaseCol,
                                                 const int* __restrict__ bucket_ptr,
                                                 unsigned* __restrict__ stagingG) {
  __shared__ int hist[NBUCK + 1], lbase[NBUCK + 1], lcur[NBUCK + 1], cbase[NBUCK];
  __shared__ int tmp[128];
  __shared__ uint2 st[EPB];
  int t = threadIdx.x, blk = blockIdx.x;
  if (t < NBUCK + 1) hist[t] = 0;
  __syncthreads();
  int e0 = blk * EPB;
#pragma unroll
  for (int it = 0; it < EPB / 512; ++it) {
    int e = e0 + it * 512 + t;
    int b = NBUCK;
    if (e < NEDGES) b = ((unsigned)edst[e]) >> 10;
    atomicAdd(&hist[b], 1);
  }
  __syncthreads();
  if (t < 128) tmp[t] = (t < NBUCK + 1) ? hist[t] : 0;
  __syncthreads();
  for (int off = 1; off < 128; off <<= 1) {
    int u = 0;
    if (t < 128 && t >= off) u = tmp[t - off];
    __syncthreads();
    if (t < 128) tmp[t] += u;
    __syncthreads();
  }
  if (t < NBUCK + 1) { int ex = tmp[t] - hist[t]; lbase[t] = ex; lcur[t] = ex; }
  if (t < NBUCK) cbase[t] = bucket_ptr[t] + blockBaseCol[t * EBLK + blk];
  __syncthreads();
#pragma unroll
  for (int it = 0; it < EPB / 512; ++it) {
    int e = e0 + it * 512 + t;
    unsigned s = 0, d = 0xFFFFFFFFu;
    if (e < NEDGES) { s = (unsigned)esrc[e]; d = (unsigned)edst[e]; }
    int b = (d == 0xFFFFFFFFu) ? NBUCK : (int)(d >> 10);
    int slot = atomicAdd(&lcur[b], 1);
    st[slot] = make_uint2(s, d);
  }
  __syncthreads();
  for (int i = t; i < EPB; i += 512) {
    uint2 ed = st[i];
    if (ed.y == 0xFFFFFFFFu) continue;
    int b = (int)(ed.y >> 10);
    stagingG[cbase[b] + (i - lbase[b])] = ((ed.y & 1023u) << 17) | ed.x;
  }
}

// fused: per-bucket degree histogram + LDS scan -> row_ptr, then scatter
__global__ __launch_bounds__(1024) void bucket_csr_fused(const unsigned* __restrict__ stagingG,
                                                         const int* __restrict__ bucket_ptr,
                                                         int* __restrict__ row_ptr,
                                                         int* __restrict__ colv) {
  __shared__ int dl[1024];
  __shared__ int cur[1024];
  int b = blockIdx.x, t = threadIdx.x;
  dl[t] = 0;
  __syncthreads();
  int s0 = bucket_ptr[b], s1 = bucket_ptr[b + 1];
  for (int j = s0 + t; j < s1; j += 1024)
    atomicAdd(&dl[stagingG[j] >> 17], 1);
  __syncthreads();
  int myDeg = dl[t];
  for (int off = 1; off < 1024; off <<= 1) {
    int u = (t >= off) ? dl[t - off] : 0;
    __syncthreads();
    dl[t] += u;
    __syncthreads();
  }
  int rp = s0 + dl[t] - myDeg;
  cur[t] = rp;
  int n = (b << 10) + t;
  if (n < NNODES) row_ptr[n] = rp;
  if (n == NNODES - 1) row_ptr[NNODES] = rp + myDeg;
  __syncthreads();
  for (int j = s0 + t; j < s1; j += 1024) {
    unsigned v = stagingG[j];
    int pos = atomicAdd(&cur[v >> 17], 1);
    colv[pos] = (int)(v & 0x1FFFFu);
  }
}

// ---------------- softmax aggregation: one wave per dst node -----------------
// fp8 payload (128B/row); weights broadcast via wave-private LDS ds_read_b64;
// both heads unpacked with one v_cvt_pk_f32_fp8; gather unrolled 8-deep.
__global__ __launch_bounds__(256) void aggregate(const unsigned short* __restrict__ hwb,
                                                 const float* __restrict__ a_s,
                                                 const float* __restrict__ a_d,
                                                 const int* __restrict__ row_ptr,
                                                 const int* __restrict__ colv,
                                                 const float* __restrict__ bias,
                                                 unsigned short* __restrict__ out) {
  __shared__ float2 wsh[256];           // 4 waves x 64 (w0,w1) entries
  int i = (blockIdx.x * 256 + threadIdx.x) >> 6;
  int lane = threadIdx.x & 63;
  if (i >= NNODES) return;
  i = __builtin_amdgcn_readfirstlane(i);
  int wbase = (threadIdx.x >> 6) * 64;

  float ad0 = a_d[2 * i], ad1 = a_d[2 * i + 1];
  int start = row_ptr[i], end = row_ptr[i + 1];
  int deg = end - start;
  float ws0 = __expf(lrelu(a_s[2 * i] + ad0));      // self edge
  float ws1 = __expf(lrelu(a_s[2 * i + 1] + ad1));

  int sl = 0; float w0l = 0.f, w1l = 0.f;
  if (lane < deg) {
    sl = colv[start + lane];
    float2 av = *reinterpret_cast<const float2*>(&a_s[2 * sl]);
    w0l = __expf(lrelu(av.x + ad0));
    w1l = __expf(lrelu(av.y + ad1));
  }
  wsh[wbase + lane] = make_float2(w0l, w1l);   // wave-private, no barrier
  float d0 = w0l, d1 = w1l;
  for (int o = 32; o; o >>= 1) { d0 += __shfl_xor(d0, o); d1 += __shfl_xor(d1, o); }
  float den0 = d0 + ws0, den1 = d1 + ws1;

  unsigned ps = hwb[(size_t)i * 64 + lane];
  f2v pv = pk_unpack_fp8(ps);
  float acc0 = ws0 * pv.x, acc1 = ws1 * pv.y;

  int dmin = deg < 64 ? deg : 64;
  int t = 0;
#define GSTEP(T)                                                               \
  {                                                                            \
    int s = __builtin_amdgcn_readlane(sl, (T));                                \
    unsigned q = hwb[(size_t)s * 64 + lane];                                   \
    float2 w = wsh[wbase + (T)];            /* ds_read_b64 broadcast */        \
    f2v xv = pk_unpack_fp8(q);                                                 \
    acc0 = fmaf(w.x, xv.x, acc0);                                              \
    acc1 = fmaf(w.y, xv.y, acc1);                                              \
  }
  for (; t + 8 <= dmin; t += 8) {
    GSTEP(t);     GSTEP(t + 1); GSTEP(t + 2); GSTEP(t + 3);
    GSTEP(t + 4); GSTEP(t + 5); GSTEP(t + 6); GSTEP(t + 7);
  }
  for (; t < dmin; ++t) { GSTEP(t); }
#undef GSTEP

  for (int j = start + 64; j < end; ++j) {   // rare overflow path (deg > 64)
    int s = colv[j];
    float2 av = *reinterpret_cast<const float2*>(&a_s[2 * s]);
    float w0 = __expf(lrelu(av.x + ad0));
    float w1 = __expf(lrelu(av.y + ad1));
    den0 += w0; den1 += w1;
    unsigned q = hwb[(size_t)s * 64 + lane];
    f2v xv = pk_unpack_fp8(q);
    acc0 = fmaf(w0, xv.x, acc0);
    acc1 = fmaf(w1, xv.y, acc1);
  }

  float r0 = fast_rcp(den0), r1 = fast_rcp(den1);
  float o0 = fmaxf(acc0 * r0 + bias[lane], 0.f);
  float o1 = fmaxf(acc1 * r1 + bias[64 + lane], 0.f);
  unsigned pk = cvt_pk_bf16(o0, o1);
  out[(size_t)i * 128 + lane]      = (unsigned short)pk;
  out[(size_t)i * 128 + 64 + lane] = (unsigned short)(pk >> 16);
}

// ---------------- per-graph pooling, node-parallel (bf16 input) --------------
// 4B-wide loads: thread tid owns column pair 2*(tid&63) and row parity
// tid>>6 -> 64 u32 loads per row instead of 128 u16 loads (halved issue
// count; atomic count unchanged at 128 per segment-chunk).
#define SEG_CHUNK 128
__global__ __launch_bounds__(128) void seg_sum_fast(const unsigned short* __restrict__ h,
                                                    const int* __restrict__ batch,
                                                    const int* __restrict__ gstart,
                                                    float* __restrict__ reprs) {
  int n0 = blockIdx.x * SEG_CHUNK;
  if (n0 >= NNODES) return;
  int nend = n0 + SEG_CHUNK; if (nend > NNODES) nend = NNODES;
  int tid = threadIdx.x;
  int half = tid >> 6;            // row parity
  int c2 = (tid & 63) * 2;        // column pair
  int r = n0;
  while (r < nend) {
    int g = batch[r];
    int segend = gstart[g + 1]; if (segend > nend) segend = nend;
    float a0 = 0.f, a1 = 0.f, b0 = 0.f, b1 = 0.f;
    int rr = r + half;
    for (; rr + 2 < segend; rr += 4) {
      unsigned u = *(const unsigned*)&h[(size_t)rr * 128 + c2];
      unsigned v = *(const unsigned*)&h[(size_t)(rr + 2) * 128 + c2];
      a0 += bf_lo(u); a1 += bf_hi(u);
      b0 += bf_lo(v); b1 += bf_hi(v);
    }
    if (rr < segend) {
      unsigned u = *(const unsigned*)&h[(size_t)rr * 128 + c2];
      a0 += bf_lo(u); a1 += bf_hi(u);
    }
    atomicAdd(&reprs[g * 128 + c2],     a0 + b0);
    atomicAdd(&reprs[g * 128 + c2 + 1], a1 + b1);
    r = segend;
  }
}

// ---------------- head MLP + log_softmax -------------------------------------
__global__ __launch_bounds__(128) void head_kernel(const float* __restrict__ reprs,
                                                   const float* __restrict__ pw1,
                                                   const float* __restrict__ pb1,
                                                   const float* __restrict__ pw2,
                                                   const float* __restrict__ pb2,
                                                   float* __restrict__ out) {
  __shared__ float r[128], t1[128], z[NCLS];
  int g = blockIdx.x, tid = threadIdx.x;
  r[tid] = reprs[g * 128 + tid];
  __syncthreads();
  float acc = pb1[tid];
  for (int k = 0; k < 128; ++k) acc = fmaf(r[k], pw1[k * 128 + tid], acc);
  t1[tid] = fmaxf(acc, 0.f);
  __syncthreads();
  if (tid < NCLS) {
    float zz = pb2[tid];
    for (int k = 0; k < 128; ++k) zz = fmaf(t1[k], pw2[k * NCLS + tid], zz);
    z[tid] = zz;
  }
  __syncthreads();
  if (tid == 0) {
    float mx = -1e30f;
    for (int c = 0; c < NCLS; ++c) mx = fmaxf(mx, z[c]);
    float s = 0.f;
    for (int c = 0; c < NCLS; ++c) s += expf(z[c] - mx);
    float ls = logf(s) + mx;
    for (int c = 0; c < NCLS; ++c) out[g * NCLS + c] = z[c] - ls;
  }
}

extern "C" void kernel_launch(void* const* d_in, const int* in_sizes, int n_in,
                              void* d_out, int out_size, void* d_ws, size_t ws_size,
                              hipStream_t stream) {
  const float* x     = (const float*)d_in[0];
  const int*   eidx  = (const int*)d_in[1];
  const int*   batch = (const int*)d_in[2];
  const float* pre_w = (const float*)d_in[3];
  const float* pre_b = (const float*)d_in[4];
  const float* w1    = (const float*)d_in[5];
  const float* asrc1 = (const float*)d_in[6];
  const float* adst1 = (const float*)d_in[7];
  const float* b1    = (const float*)d_in[8];
  const float* w2    = (const float*)d_in[9];
  const float* asrc2 = (const float*)d_in[10];
  const float* adst2 = (const float*)d_in[11];
  const float* b2    = (const float*)d_in[12];
  const float* pw1   = (const float*)d_in[13];
  const float* pb1   = (const float*)d_in[14];
  const float* pw2   = (const float*)d_in[15];
  const float* pb2   = (const float*)d_in[16];
  float* out = (float*)d_out;

  const int* esrc = eidx;
  const int* edst = eidx + NEDGES;

  char* wsp = (char*)d_ws;
  size_t off = 0;
  auto alloc = [&](size_t bytes) -> void* {
    void* p = wsp + off;
    off += (bytes + 255) & ~(size_t)255;
    return p;
  };
  unsigned short* hb  = (unsigned short*)alloc((size_t)NNODES * 128 * 2);
  unsigned short* hwb = (unsigned short*)alloc((size_t)NNODES * 64 * 2);   // fp8 pairs
  float* a_s         = (float*)alloc((size_t)NNODES * 2 * 4);
  float* a_d         = (float*)alloc((size_t)NNODES * 2 * 4);
  float* reprs       = (float*)alloc((size_t)NGRAPH * 128 * 4);
  int* gstart        = (int*)alloc((NGRAPH + 1) * 4);
  int* row_ptr       = (int*)alloc(((size_t)NNODES + 1) * 4);
  int* colv          = (int*)alloc((size_t)NEDGES * 4);
  unsigned short* wt_pre = (unsigned short*)alloc((size_t)128 * FIN * 2);
  unsigned short* wt1    = (unsigned short*)alloc((size_t)128 * HDIM * 2);
  unsigned short* wt2    = (unsigned short*)alloc((size_t)128 * HDIM * 2);
  int* blockHist     = (int*)alloc((size_t)EBLK * NBUCK * 4);
  int* blockBaseCol  = (int*)alloc((size_t)NBUCK * EBLK * 4);
  int* bucket_total  = (int*)alloc(NBUCK * 4);
  int* bucket_ptr    = (int*)alloc((NBUCK + 1) * 4);
  unsigned* stagingG = (unsigned*)alloc((size_t)NEDGES * 4);

  int wb = NNODES / 4;             // wave-per-node kernels: 256 thr = 4 waves
  int sb = (NNODES + SEG_CHUNK - 1) / SEG_CHUNK;
  int gb = (NNODES + 63) / 64;     // 1563 GEMM blocks (64-row tiles)

  // one-shot weight conversion (bf16, transposed) + find_starts, ONE launch
  convert_all<<<((FIN + 2 * HDIM) * 128 + 255) / 256, 256, 0, stream>>>(
      pre_w, w1, w2, wt_pre, wt1, wt2, batch, gstart);

  // zeroed pooling accumulator
  hipMemsetAsync(reprs, 0, (size_t)NGRAPH * 128 * 4, stream);

  // bucketed CSR build (packed 4B staging; fused deg-scan + scatter)
  bin_count<<<EBLK, 256, 0, stream>>>(edst, blockHist);
  colscan<<<NBUCK, 512, 0, stream>>>(blockHist, blockBaseCol, bucket_total);
  bscan<<<1, 128, 0, stream>>>(bucket_total, bucket_ptr);
  bin_place<<<EBLK, 512, 0, stream>>>(esrc, edst, blockBaseCol, bucket_ptr, stagingG);
  bucket_csr_fused<<<NBUCK, 1024, 0, stream>>>(stagingG, bucket_ptr, row_ptr, colv);

  // pre layer: h0 = relu(x @ pre_w + pre_b)  (bf16 h)
  gemm_gll<FIN, 0><<<gb, 256, 0, stream>>>(x, wt_pre, pre_b, hb, nullptr,
                                           nullptr, nullptr, nullptr, nullptr, NNODES, 1);
  seg_sum_fast<<<sb, 128, 0, stream>>>(hb, batch, gstart, reprs);

  // GAT layer 1 (bf16 A; alpha fused into GEMM epilogue; fp8 value payload)
  gemm_gll<HDIM, 1><<<gb, 256, 0, stream>>>(hb, wt1, nullptr, nullptr, hwb,
                                            asrc1, adst1, a_s, a_d, NNODES, 0);
  aggregate<<<wb, 256, 0, stream>>>(hwb, a_s, a_d, row_ptr, colv, b1, hb);
  seg_sum_fast<<<sb, 128, 0, stream>>>(hb, batch, gstart, reprs);

  // GAT layer 2
  gemm_gll<HDIM, 1><<<gb, 256, 0, stream>>>(hb, wt2, nullptr, nullptr, hwb,
                                            asrc2, adst2, a_s, a_d, NNODES, 0);
  aggregate<<<wb, 256, 0, stream>>>(hwb, a_s, a_d, row_ptr, colv, b2, hb);
  seg_sum_fast<<<sb, 128, 0, stream>>>(hb, batch, gstart, reprs);

  // head
  head_kernel<<<NGRAPH, 128, 0, stream>>>(reprs, pw1, pb1, pw2, pb2, out);
}